// Round 4
// baseline (379.705 us; speedup 1.0000x reference)
//
#include <hip/hip_runtime.h>

typedef __bf16 bf16_t;
typedef __bf16 bf16x8 __attribute__((ext_vector_type(8)));
typedef float f32x4 __attribute__((ext_vector_type(4)));
typedef int   int4v __attribute__((ext_vector_type(4)));

#define LOG2E 1.4426950408889634f

template<int CTRL>
__device__ __forceinline__ float qperm(float x) {
  return __builtin_bit_cast(float,
      __builtin_amdgcn_update_dpp(0, __builtin_bit_cast(int, x), CTRL, 0xF, 0xF, true));
}

// LDS-only barrier: does NOT drain vmcnt, so global loads/stores stay in
// flight across steps (compiler's __syncthreads drains vmcnt(0) every step).
__device__ __forceinline__ void lds_barrier() {
  asm volatile("s_waitcnt lgkmcnt(0)\n\ts_barrier" ::: "memory");
}

// ---------------------------------------------------------------------------
// K1: preT[dir][r][t] = (Wih_dir @ x[t_x]) + bih + bhh, gate-interleaved rows:
//     r = 4n + p  <->  original row j = 125*p + n   (n<125 valid, else 0)
//     t_x = t (fwd) or 511-t (bwd).
// MFMA GEMM with bf16 hi/lo split (fp32-exact to ~2^-18).
// grid = 64 blocks (dir*32 + row-tile T), 256 threads (4 waves).
// ---------------------------------------------------------------------------
__global__ __launch_bounds__(256) void pre_kernel(
    const float* __restrict__ x,     // [512][125]
    const float* __restrict__ Wih_f, const float* __restrict__ bih_f,
    const float* __restrict__ bhh_f,
    const float* __restrict__ Wih_b, const float* __restrict__ bih_b,
    const float* __restrict__ bhh_b,
    float* __restrict__ preT)        // [2][512 r][512 t]
{
  const int dir = blockIdx.x >> 5;
  const int T   = blockIdx.x & 31;
  const float* __restrict__ Wih = dir ? Wih_b : Wih_f;
  const float* __restrict__ bih = dir ? bih_b : bih_f;
  const float* __restrict__ bhh = dir ? bhh_b : bhh_f;

  const int tid = threadIdx.x;
  const int wv  = tid >> 6;
  const int lane = tid & 63;
  const int q = lane >> 4, cc = lane & 15;

  // A fragments: row r = 16T + cc, k = 32ks + 8q + j
  const int r  = 16 * T + cc;
  const int na = r >> 2, pa = r & 3;
  const bool vld = (na < 125);
  const float* __restrict__ Wr = Wih + (vld ? (125 * pa + na) * 125 : 0);

  bf16x8 whi[4], wlo[4];
  #pragma unroll
  for (int ks = 0; ks < 4; ++ks) {
    #pragma unroll
    for (int j = 0; j < 8; ++j) {
      int k = 32 * ks + 8 * q + j;
      float wvv = (vld && k < 125) ? Wr[k] : 0.0f;
      bf16_t hi = (bf16_t)wvv;
      whi[ks][j] = hi;
      wlo[ks][j] = (bf16_t)(wvv - (float)hi);
    }
  }

  float bias[4];
  #pragma unroll
  for (int reg = 0; reg < 4; ++reg) {
    int ro = 16 * T + 4 * q + reg;
    int no = ro >> 2, po = ro & 3;
    bias[reg] = (no < 125) ? (bih[125 * po + no] + bhh[125 * po + no]) : 0.0f;
  }

  for (int i = 0; i < 8; ++i) {
    const int tt = 8 * wv + i;
    const int t  = 16 * tt + cc;
    const int trow = dir ? (511 - t) : t;
    const float* __restrict__ xr = x + trow * 125;

    f32x4 acc = (f32x4)0.0f;
    #pragma unroll
    for (int ks = 0; ks < 4; ++ks) {
      bf16x8 xhi, xlo;
      #pragma unroll
      for (int j = 0; j < 8; ++j) {
        int k = 32 * ks + 8 * q + j;
        float xv = (k < 125) ? xr[k] : 0.0f;
        bf16_t hi = (bf16_t)xv;
        xhi[j] = hi;
        xlo[j] = (bf16_t)(xv - (float)hi);
      }
      acc = __builtin_amdgcn_mfma_f32_16x16x32_bf16(whi[ks], xhi, acc, 0, 0, 0);
      acc = __builtin_amdgcn_mfma_f32_16x16x32_bf16(whi[ks], xlo, acc, 0, 0, 0);
      acc = __builtin_amdgcn_mfma_f32_16x16x32_bf16(wlo[ks], xhi, acc, 0, 0, 0);
    }
    #pragma unroll
    for (int reg = 0; reg < 4; ++reg) {
      int ro = 16 * T + 4 * q + reg;
      preT[dir * 262144 + ro * 512 + 16 * tt + cc] = acc[reg] + bias[reg];
    }
  }
}

// ---------------------------------------------------------------------------
// K2: sequential LSTM.  grid = 2 blocks (dir), 256 threads (4 waves).
// Whh@h via mfma_i32_16x16x64_i8.  Each wave owns 8 m-tiles (T = 8w+LT);
// each lane runs TWO gate/cell chains (units n0 = 32w+4lt+q and n1 = n0+16).
// 1 wave/SIMD: MFMA pipe fed by 8 independent 2-chains; LDS reads halved
// vs the 8-wave version.
// ---------------------------------------------------------------------------
__global__ __launch_bounds__(256, 1) void lstm_kernel(
    const float* __restrict__ Whh_f, const float* __restrict__ Whh_b,
    const float* __restrict__ pre,   // [2][512 r][512 t]
    bf16_t* __restrict__ h_all)      // [512][256]  (0:125 fwd | 125:250 bwd | 250:256 zero)
{
  const int dir = blockIdx.x;
  const float* __restrict__ Whh = dir ? Whh_b : Whh_f;

  const int tid  = threadIdx.x;
  const int lane = tid & 63;
  const int w    = tid >> 6;      // wave 0..3
  const int q    = lane >> 4;     // 0..3
  const int cc   = lane & 15;
  const int lt   = cc >> 2;       // 0..3
  const int p    = cc & 3;        // gate index

  // ---- pass 1: global max |Whh| ----
  float wm = 0.0f;
  #pragma unroll
  for (int LT = 0; LT < 8; ++LT) {
    int rr = 16 * (8 * w + LT) + cc;
    int nn = rr >> 2, pp = rr & 3;
    if (nn < 125) {
      const float* __restrict__ Wrow = Whh + (125 * pp + nn) * 125;
      #pragma unroll
      for (int ks = 0; ks < 2; ++ks)
        #pragma unroll
        for (int jj = 0; jj < 16; ++jj) {
          int k = 64 * ks + 16 * q + jj;
          if (k < 125) wm = fmaxf(wm, fabsf(Wrow[k]));
        }
    }
  }
  #pragma unroll
  for (int off = 1; off < 64; off <<= 1)
    wm = fmaxf(wm, __shfl_xor(wm, off));
  __shared__ float wmx[4];
  if (lane == 0) wmx[w] = wm;
  __syncthreads();
  float wmax = fmaxf(fmaxf(wmx[0], wmx[1]), fmaxf(wmx[2], wmx[3]));
  const float s_w  = 127.0f / wmax;
  const float invq = wmax / (127.0f * 127.0f);   // D -> W@h

  // ---- pass 2: quantize A fragments (i8, k = 64ks + 16q + jj) ----
  int4v afrag[8][2];
  #pragma unroll
  for (int LT = 0; LT < 8; ++LT) {
    int rr = 16 * (8 * w + LT) + cc;
    int nn = rr >> 2, pp = rr & 3;
    bool avld = (nn < 125);
    const float* __restrict__ Wrow = Whh + (avld ? (125 * pp + nn) * 125 : 0);
    #pragma unroll
    for (int ks = 0; ks < 2; ++ks) {
      int4v v;
      #pragma unroll
      for (int word = 0; word < 4; ++word) {
        int b = 0;
        #pragma unroll
        for (int byte = 0; byte < 4; ++byte) {
          int jj = 4 * word + byte;
          int k  = 64 * ks + 16 * q + jj;
          int qv = 0;
          if (avld && k < 125)
            qv = (int)__builtin_rintf(Wrow[k] * s_w);
          b |= (qv & 0xFF) << (8 * byte);
        }
        v[word] = b;
      }
      afrag[LT][ks] = v;
    }
  }

  __shared__ __align__(16) char hbuf[2][128];    // int8 h, double buffered
  hbuf[tid >> 7][tid & 127] = 0;
  // zero h_all pad columns once (dir 0 only)
  if (dir == 0) {
    #pragma unroll
    for (int rr = 0; rr < 2; ++rr)
      #pragma unroll
      for (int u = 0; u < 6; ++u)
        h_all[(tid + 256 * rr) * 256 + 250 + u] = (bf16_t)0.0f;
  }
  __syncthreads();

  // lane owns gate rows r0 (tile 8w+lt, reg p) and r1 = r0+64 (tile 8w+4+lt)
  const int   r0  = 128 * w + 16 * lt + 4 * q + p;
  const int   r1  = r0 + 64;
  const int   n0  = 32 * w + 4 * lt + q;
  const int   n1  = n0 + 16;
  const float mult   = (p == 2) ? (-2.0f * LOG2E) : (-LOG2E);
  const float sA     = (p == 2) ? 2.0f : 1.0f;
  const float sB     = (p == 2) ? -1.0f : 0.0f;
  const float dscale = mult * invq;              // int D -> exp2 argument
  const float* __restrict__ preR0 = pre + dir * 262144 + r0 * 512;
  const float* __restrict__ preR1 = pre + dir * 262144 + r1 * 512;
  float c0 = 0.0f, c1 = 0.0f;

  float4 pv0_cur = *(const float4*)preR0;
  float4 pv1_cur = *(const float4*)preR1;

  for (int g = 0; g < 128; ++g) {
    float4 pv0_nxt = make_float4(0.f, 0.f, 0.f, 0.f);
    float4 pv1_nxt = pv0_nxt;
    if (g < 127) {
      pv0_nxt = *(const float4*)(preR0 + 4 * (g + 1));
      pv1_nxt = *(const float4*)(preR1 + 4 * (g + 1));
    }

    #pragma unroll
    for (int s4 = 0; s4 < 4; ++s4) {
      const int step = 4 * g + s4;
      const int cur  = s4 & 1, nxt = cur ^ 1;
      const float pv0 = (s4 == 0) ? pv0_cur.x : (s4 == 1) ? pv0_cur.y
                      : (s4 == 2) ? pv0_cur.z : pv0_cur.w;
      const float pv1 = (s4 == 0) ? pv1_cur.x : (s4 == 1) ? pv1_cur.y
                      : (s4 == 2) ? pv1_cur.z : pv1_cur.w;
      const float pvm0 = mult * pv0;             // off critical path
      const float pvm1 = mult * pv1;

      int4v b0 = *(const int4v*)&hbuf[cur][16 * q];
      int4v b1 = *(const int4v*)&hbuf[cur][64 + 16 * q];

      int4v acc[8];
      #pragma unroll
      for (int LT = 0; LT < 8; ++LT) {
        int4v a = (int4v)0;
        a = __builtin_amdgcn_mfma_i32_16x16x64_i8(afrag[LT][0], b0, a, 0, 0, 0);
        a = __builtin_amdgcn_mfma_i32_16x16x64_i8(afrag[LT][1], b1, a, 0, 0, 0);
        acc[LT] = a;
      }

      // gsel0 = acc[lt][p], gsel1 = acc[4+lt][p]
      int4v v01  = (lt & 1) ? acc[1] : acc[0];
      int4v v23  = (lt & 1) ? acc[3] : acc[2];
      int4v vA   = (lt & 2) ? v23 : v01;
      int4v v45  = (lt & 1) ? acc[5] : acc[4];
      int4v v67  = (lt & 1) ? acc[7] : acc[6];
      int4v vB   = (lt & 2) ? v67 : v45;
      int a01 = (p & 1) ? vA[1] : vA[0];
      int a23 = (p & 1) ? vA[3] : vA[2];
      int gsel0 = (p & 2) ? a23 : a01;
      int b01v = (p & 1) ? vB[1] : vB[0];
      int b23v = (p & 1) ? vB[3] : vB[2];
      int gsel1 = (p & 2) ? b23v : b01v;

      // uniform activation: act = sA*sigmoid(scale*(W@h + pv)) + sB
      float xg0 = fmaf((float)gsel0, dscale, pvm0);
      float xg1 = fmaf((float)gsel1, dscale, pvm1);
      float e0  = __builtin_amdgcn_exp2f(xg0);
      float e1  = __builtin_amdgcn_exp2f(xg1);
      float y0  = __builtin_amdgcn_rcpf(1.0f + e0);
      float y1  = __builtin_amdgcn_rcpf(1.0f + e1);
      float act0 = fmaf(y0, sA, sB);
      float act1 = fmaf(y1, sA, sB);

      // quad p0=i, p1=f, p2=g~, p3=o  (flat broadcasts)
      float i0v = qperm<0x00>(act0), f0v = qperm<0x55>(act0);
      float g0v = qperm<0xAA>(act0), o0v = qperm<0xFF>(act0);
      float i1v = qperm<0x00>(act1), f1v = qperm<0x55>(act1);
      float g1v = qperm<0xAA>(act1), o1v = qperm<0xFF>(act1);
      c0 = fmaf(f0v, c0, i0v * g0v);
      c1 = fmaf(f1v, c1, i1v * g1v);
      float ec0 = __builtin_amdgcn_exp2f(-2.0f * LOG2E * c0);
      float ec1 = __builtin_amdgcn_exp2f(-2.0f * LOG2E * c1);
      float tc0 = fmaf(__builtin_amdgcn_rcpf(1.0f + ec0), 2.0f, -1.0f);
      float tc1 = fmaf(__builtin_amdgcn_rcpf(1.0f + ec1), 2.0f, -1.0f);
      float h0 = o0v * tc0;
      float h1 = o1v * tc1;

      if (p == 0) {
        hbuf[nxt][n0] = (char)(int)__builtin_rintf(h0 * 127.0f);
        hbuf[nxt][n1] = (char)(int)__builtin_rintf(h1 * 127.0f);
        int t_orig = dir ? (511 - step) : step;
        h_all[t_orig * 256 + dir * 125 + n0] = (bf16_t)h0;   // n0 <= 111 < 125
        if (n1 < 125)
          h_all[t_orig * 256 + dir * 125 + n1] = (bf16_t)h1;
      }
      lds_barrier();
    }
    pv0_cur = pv0_nxt;
    pv1_cur = pv1_nxt;
  }
}

// ---------------------------------------------------------------------------
// K3: Qa[j][m] = C2 * (h @ W1[:, :250].T),  Qb[j][m] = C2 * (h @ W1[:, 250:].T + b1)
//     C2 = 2*log2(e) folded in for K4's exp2.  bf16 MFMA, one 16x16 tile/wave.
// ---------------------------------------------------------------------------
__global__ __launch_bounds__(256) void qgemm_kernel(
    const bf16_t* __restrict__ h_all, // [512][256]
    const float* __restrict__ W1,     // [512][500]
    const float* __restrict__ b1,     // [512]
    float* __restrict__ Qa,           // [512][512]
    float* __restrict__ Qb)           // [512][512]
{
  const int tid  = threadIdx.x;
  const int wv   = tid >> 6;
  const int lane = tid & 63;
  const int q    = lane >> 4, cc = lane & 15;
  const int bj   = blockIdx.x & 31;    // j tile
  const int bm   = blockIdx.x >> 5;    // m group
  const int m    = bm * 64 + wv * 16 + cc;   // [0,1024)
  const int j0   = bj * 16;
  const int jA   = j0 + cc;

  const bool isB = (m >= 512);
  const int  row = isB ? (m - 512) : m;
  const int  cof = isB ? 250 : 0;

  f32x4 acc = (f32x4)0.0f;
  #pragma unroll
  for (int ks = 0; ks < 8; ++ks) {
    int kb = 32 * ks + 8 * q;
    bf16x8 a = *(const bf16x8*)&h_all[jA * 256 + kb];
    bf16x8 b;
    #pragma unroll
    for (int jj = 0; jj < 8; ++jj) {
      int k = kb + jj;
      float v = (k < 250) ? W1[row * 500 + cof + k] : 0.0f;
      b[jj] = (bf16_t)v;
    }
    acc = __builtin_amdgcn_mfma_f32_16x16x32_bf16(a, b, acc, 0, 0, 0);
  }

  const float C2 = 2.0f * LOG2E;
  #pragma unroll
  for (int reg = 0; reg < 4; ++reg) {
    int j = j0 + 4 * q + reg;
    float v = acc[reg];
    if (!isB) Qa[j * 512 + m] = C2 * v;
    else      Qb[j * 512 + (m - 512)] = C2 * (v + b1[m - 512]);
  }
}

// ---------------------------------------------------------------------------
// K4: out[i][j] = b2 + sum_k W2[k] * tanh(...)
//     tanh = 1 - 2*rcp(1 + exp2(sa[j,k] + sb[i,k]))   (C2 pre-folded)
//     split-K x2 (512 blocks, 2/CU) so the quarter-rate trans pipe saturates;
//     partials combined via atomicAdd into a pre-zeroed out.
// ---------------------------------------------------------------------------
__global__ __launch_bounds__(256) void outer_kernel(
    const float* __restrict__ Qa, const float* __restrict__ Qb,
    const float* __restrict__ W2, const float* __restrict__ b2,
    float* __restrict__ out)
{
  __shared__ float sa[2][32][33];
  __shared__ float sb[2][32][33];
  __shared__ float sw[2][32];

  const int tid  = threadIdx.x;
  const int bk   = blockIdx.x >> 8;          // k half 0/1
  const int tile = blockIdx.x & 255;
  const int bi   = tile >> 4, bjx = tile & 15;
  const int i0   = bi * 32, j0 = bjx * 32;
  const int ii0  = (tid & 15) * 2;
  const int jj0  = (tid >> 4) * 2;
  const int ljj  = tid & 31, kk4 = (tid >> 5) * 4;
  const int kbase = bk * 256;

  float accR[2][2] = {{0.0f, 0.0f}, {0.0f, 0.0f}};
  float wsum = 0.0f;

  for (int kc = 0; kc < 8; ++kc) {
    const int buf = kc & 1;
    const int k0  = kbase + kc * 32;
    float4 va = *(const float4*)&Qa[(j0 + ljj) * 512 + k0 + kk4];
    float4 vb = *(const float4*)&Qb[(i0 + ljj) * 512 + k0 + kk4];
    sa[buf][kk4 + 0][ljj] = va.x; sa[buf][kk4 + 1][ljj] = va.y;
    sa[buf][kk4 + 2][ljj] = va.z; sa[buf][kk4 + 3][ljj] = va.w;
    sb[buf][kk4 + 0][ljj] = vb.x; sb[buf][kk4 + 1][ljj] = vb.y;
    sb[buf][kk4 + 2][ljj] = vb.z; sb[buf][kk4 + 3][ljj] = vb.w;
    if (tid < 32) sw[buf][tid] = W2[k0 + tid];
    __syncthreads();

    #pragma unroll 4
    for (int kk = 0; kk < 32; ++kk) {
      float2 av = *(const float2*)&sa[buf][kk][jj0];
      float2 bv = *(const float2*)&sb[buf][kk][ii0];
      float wk = sw[buf][kk];
      wsum += wk;
      {
        float e = __builtin_amdgcn_exp2f(av.x + bv.x);
        accR[0][0] = fmaf(wk, __builtin_amdgcn_rcpf(1.0f + e), accR[0][0]);
      }
      {
        float e = __builtin_amdgcn_exp2f(av.y + bv.x);
        accR[0][1] = fmaf(wk, __builtin_amdgcn_rcpf(1.0f + e), accR[0][1]);
      }
      {
        float e = __builtin_amdgcn_exp2f(av.x + bv.y);
        accR[1][0] = fmaf(wk, __builtin_amdgcn_rcpf(1.0f + e), accR[1][0]);
      }
      {
        float e = __builtin_amdgcn_exp2f(av.y + bv.y);
        accR[1][1] = fmaf(wk, __builtin_amdgcn_rcpf(1.0f + e), accR[1][1]);
      }
    }
  }

  const float bb = (bk == 0) ? b2[0] : 0.0f;
  #pragma unroll
  for (int i2 = 0; i2 < 2; ++i2)
    #pragma unroll
    for (int j2 = 0; j2 < 2; ++j2)
      atomicAdd(&out[(i0 + ii0 + i2) * 512 + (j0 + jj0 + j2)],
                wsum - 2.0f * accR[i2][j2] + bb);
}

// ---------------------------------------------------------------------------
extern "C" void kernel_launch(void* const* d_in, const int* in_sizes, int n_in,
                              void* d_out, int out_size, void* d_ws, size_t ws_size,
                              hipStream_t stream) {
  const float* emb   = (const float*)d_in[0];
  const float* Wih_f = (const float*)d_in[1];
  const float* Whh_f = (const float*)d_in[2];
  const float* bih_f = (const float*)d_in[3];
  const float* bhh_f = (const float*)d_in[4];
  const float* Wih_b = (const float*)d_in[5];
  const float* Whh_b = (const float*)d_in[6];
  const float* bih_b = (const float*)d_in[7];
  const float* bhh_b = (const float*)d_in[8];
  const float* W1    = (const float*)d_in[9];
  const float* b1    = (const float*)d_in[10];
  const float* W2    = (const float*)d_in[11];
  const float* b2    = (const float*)d_in[12];
  float* out = (float*)d_out;

  char* ws = (char*)d_ws;
  float*  pre   = (float*)ws;                                  // 2 MB
  bf16_t* h_all = (bf16_t*)(ws + 2 * 1024 * 1024);             // 256 KB
  float*  Qa    = (float*)(ws + 2 * 1024 * 1024 + 256 * 1024); // 1 MB
  float*  Qb    = Qa + 512 * 512;                              // 1 MB

  pre_kernel<<<64, 256, 0, stream>>>(emb, Wih_f, bih_f, bhh_f,
                                     Wih_b, bih_b, bhh_b, pre);
  lstm_kernel<<<2, 256, 0, stream>>>(Whh_f, Whh_b, pre, h_all);
  qgemm_kernel<<<512, 256, 0, stream>>>(h_all, W1, b1, Qa, Qb);
  hipMemsetAsync(out, 0, (size_t)out_size * sizeof(float), stream);
  outer_kernel<<<512, 256, 0, stream>>>(Qa, Qb, W2, b2, out);
}

// Round 5
// 355.776 us; speedup vs baseline: 1.0673x; 1.0673x over previous
//
#include <hip/hip_runtime.h>

typedef __bf16 bf16_t;
typedef __bf16 bf16x8 __attribute__((ext_vector_type(8)));
typedef float f32x4 __attribute__((ext_vector_type(4)));
typedef int   int4v __attribute__((ext_vector_type(4)));

#define LOG2E 1.4426950408889634f

template<int CTRL>
__device__ __forceinline__ float qperm(float x) {
  return __builtin_bit_cast(float,
      __builtin_amdgcn_update_dpp(0, __builtin_bit_cast(int, x), CTRL, 0xF, 0xF, true));
}

// LDS-only barrier: does NOT drain vmcnt, so global loads/stores stay in
// flight across steps (compiler's __syncthreads drains vmcnt(0) every step).
__device__ __forceinline__ void lds_barrier() {
  asm volatile("s_waitcnt lgkmcnt(0)\n\ts_barrier" ::: "memory");
}

// ---------------------------------------------------------------------------
// K1: preT[dir][r][t] = (Wih_dir @ x[t_x]) + bih + bhh, gate-interleaved rows:
//     r = 4n + p  <->  original row j = 125*p + n   (n<125 valid, else 0)
//     t_x = t (fwd) or 511-t (bwd).
// MFMA GEMM with bf16 hi/lo split (fp32-exact to ~2^-18).
// grid = 64 blocks (dir*32 + row-tile T), 256 threads (4 waves).
// ---------------------------------------------------------------------------
__global__ __launch_bounds__(256) void pre_kernel(
    const float* __restrict__ x,     // [512][125]
    const float* __restrict__ Wih_f, const float* __restrict__ bih_f,
    const float* __restrict__ bhh_f,
    const float* __restrict__ Wih_b, const float* __restrict__ bih_b,
    const float* __restrict__ bhh_b,
    float* __restrict__ preT)        // [2][512 r][512 t]
{
  const int dir = blockIdx.x >> 5;
  const int T   = blockIdx.x & 31;
  const float* __restrict__ Wih = dir ? Wih_b : Wih_f;
  const float* __restrict__ bih = dir ? bih_b : bih_f;
  const float* __restrict__ bhh = dir ? bhh_b : bhh_f;

  const int tid = threadIdx.x;
  const int wv  = tid >> 6;
  const int lane = tid & 63;
  const int q = lane >> 4, cc = lane & 15;

  // A fragments: row r = 16T + cc, k = 32ks + 8q + j
  const int r  = 16 * T + cc;
  const int na = r >> 2, pa = r & 3;
  const bool vld = (na < 125);
  const float* __restrict__ Wr = Wih + (vld ? (125 * pa + na) * 125 : 0);

  bf16x8 whi[4], wlo[4];
  #pragma unroll
  for (int ks = 0; ks < 4; ++ks) {
    #pragma unroll
    for (int j = 0; j < 8; ++j) {
      int k = 32 * ks + 8 * q + j;
      float wvv = (vld && k < 125) ? Wr[k] : 0.0f;
      bf16_t hi = (bf16_t)wvv;
      whi[ks][j] = hi;
      wlo[ks][j] = (bf16_t)(wvv - (float)hi);
    }
  }

  float bias[4];
  #pragma unroll
  for (int reg = 0; reg < 4; ++reg) {
    int ro = 16 * T + 4 * q + reg;
    int no = ro >> 2, po = ro & 3;
    bias[reg] = (no < 125) ? (bih[125 * po + no] + bhh[125 * po + no]) : 0.0f;
  }

  for (int i = 0; i < 8; ++i) {
    const int tt = 8 * wv + i;
    const int t  = 16 * tt + cc;
    const int trow = dir ? (511 - t) : t;
    const float* __restrict__ xr = x + trow * 125;

    f32x4 acc = (f32x4)0.0f;
    #pragma unroll
    for (int ks = 0; ks < 4; ++ks) {
      bf16x8 xhi, xlo;
      #pragma unroll
      for (int j = 0; j < 8; ++j) {
        int k = 32 * ks + 8 * q + j;
        float xv = (k < 125) ? xr[k] : 0.0f;
        bf16_t hi = (bf16_t)xv;
        xhi[j] = hi;
        xlo[j] = (bf16_t)(xv - (float)hi);
      }
      acc = __builtin_amdgcn_mfma_f32_16x16x32_bf16(whi[ks], xhi, acc, 0, 0, 0);
      acc = __builtin_amdgcn_mfma_f32_16x16x32_bf16(whi[ks], xlo, acc, 0, 0, 0);
      acc = __builtin_amdgcn_mfma_f32_16x16x32_bf16(wlo[ks], xhi, acc, 0, 0, 0);
    }
    #pragma unroll
    for (int reg = 0; reg < 4; ++reg) {
      int ro = 16 * T + 4 * q + reg;
      preT[dir * 262144 + ro * 512 + 16 * tt + cc] = acc[reg] + bias[reg];
    }
  }
}

// ---------------------------------------------------------------------------
// K2: sequential LSTM.  grid = 2 blocks (dir), 1024 threads (16 waves,
// 4 waves/SIMD).  Each wave owns 2 m-tiles (T = 2w+LT) -> 4 MFMA/step;
// per-SIMD MFMA pipe time unchanged, but 4 waves overlap each other's
// ds_read latency and serial gate tails (round-4 lesson: 1 wave/SIMD
// exposes the tail fully).  Lanes lt>=2 are redundant duplicates of lt<2
// (MFMA columns replicate y anyway); only lt<2, p==0 lanes write h.
// ---------------------------------------------------------------------------
__global__ __launch_bounds__(1024, 4) void lstm_kernel(
    const float* __restrict__ Whh_f, const float* __restrict__ Whh_b,
    const float* __restrict__ pre,   // [2][512 r][512 t]
    bf16_t* __restrict__ h_all)      // [512][256]  (0:125 fwd | 125:250 bwd | 250:256 zero)
{
  const int dir = blockIdx.x;
  const float* __restrict__ Whh = dir ? Whh_b : Whh_f;

  const int tid  = threadIdx.x;
  const int lane = tid & 63;
  const int w    = tid >> 6;      // wave 0..15
  const int q    = lane >> 4;     // 0..3
  const int cc   = lane & 15;
  const int lt   = cc >> 2;       // 0..3
  const int p    = cc & 3;        // gate index
  const int ltp  = lt & 1;        // which of the wave's 2 tiles this lane uses

  // ---- pass 1: global max |Whh| ----
  float wm = 0.0f;
  #pragma unroll
  for (int LT = 0; LT < 2; ++LT) {
    int rr = 16 * (2 * w + LT) + cc;
    int nn = rr >> 2, pp = rr & 3;
    if (nn < 125) {
      const float* __restrict__ Wrow = Whh + (125 * pp + nn) * 125;
      #pragma unroll
      for (int ks = 0; ks < 2; ++ks)
        #pragma unroll
        for (int jj = 0; jj < 16; ++jj) {
          int k = 64 * ks + 16 * q + jj;
          if (k < 125) wm = fmaxf(wm, fabsf(Wrow[k]));
        }
    }
  }
  #pragma unroll
  for (int off = 1; off < 64; off <<= 1)
    wm = fmaxf(wm, __shfl_xor(wm, off));
  __shared__ float wmx[16];
  if (lane == 0) wmx[w] = wm;
  __syncthreads();
  float wmax = wmx[0];
  #pragma unroll
  for (int u = 1; u < 16; ++u) wmax = fmaxf(wmax, wmx[u]);
  const float s_w  = 127.0f / wmax;
  const float invq = wmax / (127.0f * 127.0f);   // D -> W@h

  // ---- pass 2: quantize A fragments (i8, k = 64ks + 16q + jj) ----
  int4v afrag[2][2];
  #pragma unroll
  for (int LT = 0; LT < 2; ++LT) {
    int rr = 16 * (2 * w + LT) + cc;
    int nn = rr >> 2, pp = rr & 3;
    bool avld = (nn < 125);
    const float* __restrict__ Wrow = Whh + (avld ? (125 * pp + nn) * 125 : 0);
    #pragma unroll
    for (int ks = 0; ks < 2; ++ks) {
      int4v v;
      #pragma unroll
      for (int word = 0; word < 4; ++word) {
        int b = 0;
        #pragma unroll
        for (int byte = 0; byte < 4; ++byte) {
          int jj = 4 * word + byte;
          int k  = 64 * ks + 16 * q + jj;
          int qv = 0;
          if (avld && k < 125)
            qv = (int)__builtin_rintf(Wrow[k] * s_w);
          b |= (qv & 0xFF) << (8 * byte);
        }
        v[word] = b;
      }
      afrag[LT][ks] = v;
    }
  }

  __shared__ __align__(16) char hbuf[2][128];    // int8 h, double buffered
  if (tid < 256) hbuf[tid >> 7][tid & 127] = 0;
  // zero h_all pad columns once (dir 0 only)
  if (dir == 0 && tid < 512) {
    #pragma unroll
    for (int u = 0; u < 6; ++u)
      h_all[tid * 256 + 250 + u] = (bf16_t)0.0f;
  }
  __syncthreads();

  // lane's gate row (r = 4n+p) and unit
  const int   r_lane = 32 * w + 16 * ltp + 4 * q + p;
  const int   n0     = 8 * w + 4 * ltp + q;           // unit, [0,128)
  const float mult   = (p == 2) ? (-2.0f * LOG2E) : (-LOG2E);
  const float sA     = (p == 2) ? 2.0f : 1.0f;
  const float sB     = (p == 2) ? -1.0f : 0.0f;
  const float dscale = mult * invq;                   // int D -> exp2 argument
  const float* __restrict__ preR = pre + dir * 262144 + r_lane * 512;
  float c = 0.0f;

  float4 pv_cur = *(const float4*)preR;

  for (int g = 0; g < 128; ++g) {
    float4 pv_nxt = make_float4(0.f, 0.f, 0.f, 0.f);
    if (g < 127) pv_nxt = *(const float4*)(preR + 4 * (g + 1));

    #pragma unroll
    for (int s4 = 0; s4 < 4; ++s4) {
      const int step = 4 * g + s4;
      const int cur  = s4 & 1, nxt = cur ^ 1;
      const float pv = (s4 == 0) ? pv_cur.x : (s4 == 1) ? pv_cur.y
                     : (s4 == 2) ? pv_cur.z : pv_cur.w;
      const float pvm = mult * pv;               // off critical path

      int4v b0 = *(const int4v*)&hbuf[cur][16 * q];
      int4v b1 = *(const int4v*)&hbuf[cur][64 + 16 * q];

      int4v a0 = (int4v)0;
      a0 = __builtin_amdgcn_mfma_i32_16x16x64_i8(afrag[0][0], b0, a0, 0, 0, 0);
      a0 = __builtin_amdgcn_mfma_i32_16x16x64_i8(afrag[0][1], b1, a0, 0, 0, 0);
      int4v a1 = (int4v)0;
      a1 = __builtin_amdgcn_mfma_i32_16x16x64_i8(afrag[1][0], b0, a1, 0, 0, 0);
      a1 = __builtin_amdgcn_mfma_i32_16x16x64_i8(afrag[1][1], b1, a1, 0, 0, 0);

      // gsel = acc[ltp][p]
      int4v vA;
      #pragma unroll
      for (int i = 0; i < 4; ++i) vA[i] = ltp ? a1[i] : a0[i];
      int a01 = (p & 1) ? vA[1] : vA[0];
      int a23 = (p & 1) ? vA[3] : vA[2];
      int gsel = (p & 2) ? a23 : a01;

      // uniform activation: act = sA*sigmoid(scale*(W@h + pv)) + sB
      float xg  = fmaf((float)gsel, dscale, pvm);
      float e   = __builtin_amdgcn_exp2f(xg);
      float y   = __builtin_amdgcn_rcpf(1.0f + e);
      float act = fmaf(y, sA, sB);

      // quad p0=i, p1=f, p2=g~, p3=o  (flat broadcasts)
      float b_i = qperm<0x00>(act);
      float b_f = qperm<0x55>(act);
      float b_g = qperm<0xAA>(act);
      float b_o = qperm<0xFF>(act);
      c = fmaf(b_f, c, b_i * b_g);               // c = f*c + i*g~
      float e2 = __builtin_amdgcn_exp2f(-2.0f * LOG2E * c);
      float tc = fmaf(__builtin_amdgcn_rcpf(1.0f + e2), 2.0f, -1.0f);
      float h  = b_o * tc;

      if (p == 0 && lt < 2) {
        hbuf[nxt][n0] = (char)(int)__builtin_rintf(h * 127.0f);
        if (n0 < 125) {
          int t_orig = dir ? (511 - step) : step;
          h_all[t_orig * 256 + dir * 125 + n0] = (bf16_t)h;
        }
      }
      lds_barrier();
    }
    pv_cur = pv_nxt;
  }
}

// ---------------------------------------------------------------------------
// K3: Qa[j][m] = C2 * (h @ W1[:, :250].T),  Qb[j][m] = C2 * (h @ W1[:, 250:].T + b1)
//     C2 = 2*log2(e) folded in for K4's exp2.  bf16 MFMA, one 16x16 tile/wave.
// ---------------------------------------------------------------------------
__global__ __launch_bounds__(256) void qgemm_kernel(
    const bf16_t* __restrict__ h_all, // [512][256]
    const float* __restrict__ W1,     // [512][500]
    const float* __restrict__ b1,     // [512]
    float* __restrict__ Qa,           // [512][512]
    float* __restrict__ Qb)           // [512][512]
{
  const int tid  = threadIdx.x;
  const int wv   = tid >> 6;
  const int lane = tid & 63;
  const int q    = lane >> 4, cc = lane & 15;
  const int bj   = blockIdx.x & 31;    // j tile
  const int bm   = blockIdx.x >> 5;    // m group
  const int m    = bm * 64 + wv * 16 + cc;   // [0,1024)
  const int j0   = bj * 16;
  const int jA   = j0 + cc;

  const bool isB = (m >= 512);
  const int  row = isB ? (m - 512) : m;
  const int  cof = isB ? 250 : 0;

  f32x4 acc = (f32x4)0.0f;
  #pragma unroll
  for (int ks = 0; ks < 8; ++ks) {
    int kb = 32 * ks + 8 * q;
    bf16x8 a = *(const bf16x8*)&h_all[jA * 256 + kb];
    bf16x8 b;
    #pragma unroll
    for (int jj = 0; jj < 8; ++jj) {
      int k = kb + jj;
      float v = (k < 250) ? W1[row * 500 + cof + k] : 0.0f;
      b[jj] = (bf16_t)v;
    }
    acc = __builtin_amdgcn_mfma_f32_16x16x32_bf16(a, b, acc, 0, 0, 0);
  }

  const float C2 = 2.0f * LOG2E;
  #pragma unroll
  for (int reg = 0; reg < 4; ++reg) {
    int j = j0 + 4 * q + reg;
    float v = acc[reg];
    if (!isB) Qa[j * 512 + m] = C2 * v;
    else      Qb[j * 512 + (m - 512)] = C2 * (v + b1[m - 512]);
  }
}

// ---------------------------------------------------------------------------
// K4: out[i][j] = b2 + sum_k W2[k] * tanh(...)
//     tanh = 1 - 2*rcp(1 + exp2(sa[j,k] + sb[i,k]))   (C2 pre-folded)
//     split-K x2 (512 blocks, 2/CU) so the quarter-rate trans pipe saturates;
//     partials combined via atomicAdd into a pre-zeroed out.
// ---------------------------------------------------------------------------
__global__ __launch_bounds__(256) void outer_kernel(
    const float* __restrict__ Qa, const float* __restrict__ Qb,
    const float* __restrict__ W2, const float* __restrict__ b2,
    float* __restrict__ out)
{
  __shared__ float sa[2][32][33];
  __shared__ float sb[2][32][33];
  __shared__ float sw[2][32];

  const int tid  = threadIdx.x;
  const int bk   = blockIdx.x >> 8;          // k half 0/1
  const int tile = blockIdx.x & 255;
  const int bi   = tile >> 4, bjx = tile & 15;
  const int i0   = bi * 32, j0 = bjx * 32;
  const int ii0  = (tid & 15) * 2;
  const int jj0  = (tid >> 4) * 2;
  const int ljj  = tid & 31, kk4 = (tid >> 5) * 4;
  const int kbase = bk * 256;

  float accR[2][2] = {{0.0f, 0.0f}, {0.0f, 0.0f}};
  float wsum = 0.0f;

  for (int kc = 0; kc < 8; ++kc) {
    const int buf = kc & 1;
    const int k0  = kbase + kc * 32;
    float4 va = *(const float4*)&Qa[(j0 + ljj) * 512 + k0 + kk4];
    float4 vb = *(const float4*)&Qb[(i0 + ljj) * 512 + k0 + kk4];
    sa[buf][kk4 + 0][ljj] = va.x; sa[buf][kk4 + 1][ljj] = va.y;
    sa[buf][kk4 + 2][ljj] = va.z; sa[buf][kk4 + 3][ljj] = va.w;
    sb[buf][kk4 + 0][ljj] = vb.x; sb[buf][kk4 + 1][ljj] = vb.y;
    sb[buf][kk4 + 2][ljj] = vb.z; sb[buf][kk4 + 3][ljj] = vb.w;
    if (tid < 32) sw[buf][tid] = W2[k0 + tid];
    __syncthreads();

    #pragma unroll 4
    for (int kk = 0; kk < 32; ++kk) {
      float2 av = *(const float2*)&sa[buf][kk][jj0];
      float2 bv = *(const float2*)&sb[buf][kk][ii0];
      float wk = sw[buf][kk];
      wsum += wk;
      {
        float e = __builtin_amdgcn_exp2f(av.x + bv.x);
        accR[0][0] = fmaf(wk, __builtin_amdgcn_rcpf(1.0f + e), accR[0][0]);
      }
      {
        float e = __builtin_amdgcn_exp2f(av.y + bv.x);
        accR[0][1] = fmaf(wk, __builtin_amdgcn_rcpf(1.0f + e), accR[0][1]);
      }
      {
        float e = __builtin_amdgcn_exp2f(av.x + bv.y);
        accR[1][0] = fmaf(wk, __builtin_amdgcn_rcpf(1.0f + e), accR[1][0]);
      }
      {
        float e = __builtin_amdgcn_exp2f(av.y + bv.y);
        accR[1][1] = fmaf(wk, __builtin_amdgcn_rcpf(1.0f + e), accR[1][1]);
      }
    }
  }

  const float bb = (bk == 0) ? b2[0] : 0.0f;
  #pragma unroll
  for (int i2 = 0; i2 < 2; ++i2)
    #pragma unroll
    for (int j2 = 0; j2 < 2; ++j2)
      atomicAdd(&out[(i0 + ii0 + i2) * 512 + (j0 + jj0 + j2)],
                wsum - 2.0f * accR[i2][j2] + bb);
}

// ---------------------------------------------------------------------------
extern "C" void kernel_launch(void* const* d_in, const int* in_sizes, int n_in,
                              void* d_out, int out_size, void* d_ws, size_t ws_size,
                              hipStream_t stream) {
  const float* emb   = (const float*)d_in[0];
  const float* Wih_f = (const float*)d_in[1];
  const float* Whh_f = (const float*)d_in[2];
  const float* bih_f = (const float*)d_in[3];
  const float* bhh_f = (const float*)d_in[4];
  const float* Wih_b = (const float*)d_in[5];
  const float* Whh_b = (const float*)d_in[6];
  const float* bih_b = (const float*)d_in[7];
  const float* bhh_b = (const float*)d_in[8];
  const float* W1    = (const float*)d_in[9];
  const float* b1    = (const float*)d_in[10];
  const float* W2    = (const float*)d_in[11];
  const float* b2    = (const float*)d_in[12];
  float* out = (float*)d_out;

  char* ws = (char*)d_ws;
  float*  pre   = (float*)ws;                                  // 2 MB
  bf16_t* h_all = (bf16_t*)(ws + 2 * 1024 * 1024);             // 256 KB
  float*  Qa    = (float*)(ws + 2 * 1024 * 1024 + 256 * 1024); // 1 MB
  float*  Qb    = Qa + 512 * 512;                              // 1 MB

  pre_kernel<<<64, 256, 0, stream>>>(emb, Wih_f, bih_f, bhh_f,
                                     Wih_b, bih_b, bhh_b, pre);
  lstm_kernel<<<2, 1024, 0, stream>>>(Whh_f, Whh_b, pre, h_all);
  qgemm_kernel<<<512, 256, 0, stream>>>(h_all, W1, b1, Qa, Qb);
  hipMemsetAsync(out, 0, (size_t)out_size * sizeof(float), stream);
  outer_kernel<<<512, 256, 0, stream>>>(Qa, Qb, W2, b2, out);
}